// Round 8
// baseline (307.159 us; speedup 1.0000x reference)
//
#include <hip/hip_runtime.h>
#include <hip/hip_fp16.h>

namespace {

constexpr int H = 1024, W = 1024, NB = 4;
constexpr int SH = 128, SW = 128;
constexpr float LAM = 0.24f;
constexpr float KK = 0.03f * 0.03f;
constexpr float DEPS_V = 0.1f;
constexpr float FFT_SCALE = 1.0f / (1024.0f * 1024.0f);  // ortho fwd+inv combined
// Processed (masked) columns: |x(k2)| <= 0.5  <=>  k2 in [256, 768). Margin to the
// 0.25 boundary ~1.5e-3 >> fp error.
constexpr int COL_LO = 256, NCOL = 512;

__device__ __forceinline__ float2 cadd(float2 a, float2 b) { return make_float2(a.x + b.x, a.y + b.y); }
__device__ __forceinline__ float2 csub(float2 a, float2 b) { return make_float2(a.x - b.x, a.y - b.y); }
__device__ __forceinline__ float2 cmul(float2 a, float2 b) {
  return make_float2(a.x * b.x - a.y * b.y, a.x * b.y + a.y * b.x);
}
__device__ __forceinline__ int phys2(int e) { return e + (e >> 4); }

// ---------------- min(source): 2-stage parallel reduction ----------------
__global__ void k_shift_part(const float* __restrict__ src, float* __restrict__ partial) {
  int t = threadIdx.x;
  int b0 = blockIdx.x * 1024;
  float m = fminf(fminf(src[b0 + t], src[b0 + t + 256]),
                  fminf(src[b0 + t + 512], src[b0 + t + 768]));
  for (int o = 32; o > 0; o >>= 1) m = fminf(m, __shfl_xor(m, o));
  __shared__ float sm[4];
  if ((t & 63) == 0) sm[t >> 6] = m;
  __syncthreads();
  if (t == 0) partial[blockIdx.x] = fminf(fminf(sm[0], sm[1]), fminf(sm[2], sm[3]));
}

__global__ void k_shift_fin(const float* __restrict__ partial, float* __restrict__ shiftp) {
  int t = threadIdx.x;  // 64 threads
  float m = partial[t];
  for (int o = 32; o > 0; o >>= 1) m = fminf(m, __shfl_xor(m, o));
  if (t == 0) shiftp[0] = (m <= DEPS_V) ? DEPS_V : 0.0f;
}

// ---------------- Stockham radix-4 1024-pt FFT (natural in -> natural out) ----------------
template <int NS, bool INV>
__device__ __forceinline__ void r4_butterfly(float2 v[4], int j, float2 r[4]) {
  if (NS > 1) {
    int p = j & (NS - 1);
    float sn, cs;
    sincospif((INV ? 1.0f : -1.0f) * (float)p * (1.0f / (float)(2 * NS)), &sn, &cs);
    float2 w1 = make_float2(cs, sn);
    float2 w2 = cmul(w1, w1);
    float2 w3 = cmul(w2, w1);
    v[1] = cmul(v[1], w1);
    v[2] = cmul(v[2], w2);
    v[3] = cmul(v[3], w3);
  }
  float2 a0 = cadd(v[0], v[2]), a2 = csub(v[0], v[2]);
  float2 a1 = cadd(v[1], v[3]), a3 = csub(v[1], v[3]);
  a3 = INV ? make_float2(-a3.y, a3.x) : make_float2(a3.y, -a3.x);
  r[0] = cadd(a0, a1);
  r[2] = csub(a0, a1);
  r[1] = cadd(a2, a3);
  r[3] = csub(a2, a3);
}

template <int NS, bool INV>
__device__ __forceinline__ void r4_stage_lds(float2 v[4], float2* dst, int j) {
  float2 r[4];
  r4_butterfly<NS, INV>(v, j, r);
  int p = j & (NS - 1);
  int base = ((j - p) << 2) + p;
#pragma unroll
  for (int k = 0; k < 4; ++k) dst[phys2(base + k * NS)] = r[k];
}

__device__ __forceinline__ void lds_load4(const float2* src, float2 v[4], int j) {
#pragma unroll
  for (int k = 0; k < 4; ++k) v[k] = src[phys2(j + k * 256)];
}

template <bool INV>
__device__ void fft1024(float2 v[4], float2* b0, float2* b1, int j) {
  r4_stage_lds<1, INV>(v, b0, j);
  __syncthreads();
  lds_load4(b0, v, j);
  r4_stage_lds<4, INV>(v, b1, j);
  __syncthreads();
  lds_load4(b1, v, j);
  r4_stage_lds<16, INV>(v, b0, j);
  __syncthreads();
  lds_load4(b0, v, j);
  r4_stage_lds<64, INV>(v, b1, j);
  __syncthreads();
  lds_load4(b1, v, j);
  float2 r[4];
  r4_butterfly<256, INV>(v, j, r);
#pragma unroll
  for (int k = 0; k < 4; ++k) v[k] = r[k];
}

// ---------------- forward row FFT, 2 real rows packed per complex transform ----------------
// Z = S(2y) + i*S(2y+1); F0[k] = (Z[k]+conj(Z[-k]))/2, F1[k] = -i(Z[k]-conj(Z[-k]))/2.
__global__ void k_rowfft_fwd(const float* __restrict__ guide, const float* __restrict__ ybic,
                             const float* __restrict__ shiftp, float2* __restrict__ A) {
  __shared__ float2 b0[1088], b1[1088];
  int b = blockIdx.y, y0 = blockIdx.x * 2, j = threadIdx.x;
  float sh = shiftp[0];
  const float* g0 = guide + ((size_t)(b * 3 + 0) * H + y0) * W;
  const float* g1 = guide + ((size_t)(b * 3 + 1) * H + y0) * W;
  const float* g2 = guide + ((size_t)(b * 3 + 2) * H + y0) * W;
  const float* yb = ybic + ((size_t)b * H + y0) * W;
  float2 v[4];
#pragma unroll
  for (int k = 0; k < 4; ++k) {
    int x = j + k * 256;
    float s0 = g0[x] + g1[x] + g2[x] + (yb[x] + sh);
    float s1 = g0[x + W] + g1[x + W] + g2[x + W] + (yb[x + W] + sh);
    v[k] = make_float2(s0, s1);
  }
  fft1024<false>(v, b0, b1, j);
#pragma unroll
  for (int k = 0; k < 4; ++k) b0[phys2(j + k * 256)] = v[k];
  __syncthreads();
  float2* o0 = A + ((size_t)b * H + y0) * W;
  float2* o1 = o0 + W;
#pragma unroll
  for (int k = 0; k < 4; ++k) {
    int m = j + k * 256;
    float2 Zm = v[k];
    float2 Zc = b0[phys2((1024 - m) & 1023)];
    o0[m] = make_float2(0.5f * (Zm.x + Zc.x), 0.5f * (Zm.y - Zc.y));
    o1[m] = make_float2(0.5f * (Zm.y + Zc.y), 0.5f * (Zc.x - Zm.x));
  }
}

// ---------------- forward transpose: columns [256,768) -> Bc col-major ----------------
__global__ void k_transpose_fwd(const float2* __restrict__ A, float2* __restrict__ Bc) {
  __shared__ float2 tile[32][33];
  int b = blockIdx.z;
  int c0 = blockIdx.x * 32, y0 = blockIdx.y * 32;
  const float2* ip = A + (size_t)b * H * W;
  float2* op = Bc + (size_t)b * NCOL * H;
#pragma unroll
  for (int k = 0; k < 4; ++k)
    tile[threadIdx.y + k * 8][threadIdx.x] =
        ip[(size_t)(y0 + threadIdx.y + k * 8) * W + (COL_LO + c0 + threadIdx.x)];
  __syncthreads();
#pragma unroll
  for (int k = 0; k < 4; ++k)
    op[(size_t)(c0 + threadIdx.y + k * 8) * H + (y0 + threadIdx.x)] =
        tile[threadIdx.x][threadIdx.y + k * 8];
}

// ---------------- column FFT + radial mask + inverse column FFT ----------------
__global__ void k_colfft_mask(float2* __restrict__ Bc) {
  __shared__ float2 b0[1088], b1[1088];
  int b = blockIdx.y, r = blockIdx.x, j = threadIdx.x;
  int k2 = COL_LO + r;
  double xj = -1.0 + 2.0 * (double)k2 / 1023.0;
  double xj2 = xj * xj;
  float2* row = Bc + ((size_t)b * NCOL + r) * H;
  float2 v[4];
#pragma unroll
  for (int k = 0; k < 4; ++k) v[k] = row[j + k * 256];
  fft1024<false>(v, b0, b1, j);
#pragma unroll
  for (int k = 0; k < 4; ++k) {
    int i = j + k * 256;
    double yv = -1.0 + 2.0 * (double)i / 1023.0;
    if (xj2 + yv * yv <= 0.25) v[k] = make_float2(0.0f, 0.0f);
  }
  fft1024<true>(v, b0, b1, j);
#pragma unroll
  for (int k = 0; k < 4; ++k) row[j + k * 256] = v[k];
}

// ---------------- inverse row FFT with Bc gather (no backward transpose) ----------------
// 1 row/block. Pass-through cols read from A x1024; masked cols gathered directly from
// Bc col-major. Inputs identical to the round-4 fused kernel -> bit-identical er.
__global__ __launch_bounds__(256) void k_rowfft_invg(
    const float2* __restrict__ A, const float2* __restrict__ Bc, float* __restrict__ er) {
  __shared__ float2 b0[1088], b1[1088];
  int b = blockIdx.y, y = blockIdx.x, j = threadIdx.x;
  const float2* arow = A + ((size_t)b * H + y) * W;
  float2 v[4];
  float2 a0 = arow[j], a3 = arow[j + 768];
  v[0] = make_float2(a0.x * 1024.0f, a0.y * 1024.0f);
  v[3] = make_float2(a3.x * 1024.0f, a3.y * 1024.0f);
  v[1] = Bc[((size_t)b * NCOL + j) * H + y];
  v[2] = Bc[((size_t)b * NCOL + j + 256) * H + y];
  fft1024<true>(v, b0, b1, j);
  float* out = er + ((size_t)b * H + y) * W;
#pragma unroll
  for (int k = 0; k < 4; ++k) out[j + k * 256] = v[k].x * FFT_SCALE;
}

// ---------------- Perona-Malik coefficients, packed half2 {cv, ch}, 4 px/thread ----------
__global__ void k_coeffs(const float* __restrict__ guide, const float* __restrict__ ybic,
                         const float* __restrict__ er, __half2* __restrict__ cvh) {
  int b = blockIdx.y, y = blockIdx.x, t = threadIdx.x;
  int x0 = t * 4;
  const float* g = guide + (size_t)b * 3 * H * W;
  const float* yb = ybic + (size_t)b * H * W;
  const float* e = er + (size_t)b * H * W;
  __half2* cp = cvh + (size_t)b * H * W;
  const size_t CH = (size_t)H * W;
  size_t row = (size_t)y * W + x0;
  float4 a0 = *(const float4*)(g + row);
  float4 a1 = *(const float4*)(g + CH + row);
  float4 a2 = *(const float4*)(g + 2 * CH + row);
  float4 a3 = *(const float4*)(yb + row);
  float4 e0 = *(const float4*)(e + row);
  float A0[5] = {a0.x, a0.y, a0.z, a0.w, 0.f};
  float A1[5] = {a1.x, a1.y, a1.z, a1.w, 0.f};
  float A2[5] = {a2.x, a2.y, a2.z, a2.w, 0.f};
  float A3[5] = {a3.x, a3.y, a3.z, a3.w, 0.f};
  float E0[5] = {e0.x, e0.y, e0.z, e0.w, 0.f};
  bool hasR = (x0 + 4 < W);
  if (hasR) {
    A0[4] = g[row + 4]; A1[4] = g[CH + row + 4]; A2[4] = g[2 * CH + row + 4];
    A3[4] = yb[row + 4]; E0[4] = e[row + 4];
  }
  float B0[4], B1[4], B2[4], B3[4], E1[4];
  bool hasD = (y < H - 1);
  if (hasD) {
    float4 q0 = *(const float4*)(g + row + W);
    float4 q1 = *(const float4*)(g + CH + row + W);
    float4 q2 = *(const float4*)(g + 2 * CH + row + W);
    float4 q3 = *(const float4*)(yb + row + W);
    float4 q4 = *(const float4*)(e + row + W);
    B0[0]=q0.x; B0[1]=q0.y; B0[2]=q0.z; B0[3]=q0.w;
    B1[0]=q1.x; B1[1]=q1.y; B1[2]=q1.z; B1[3]=q1.w;
    B2[0]=q2.x; B2[1]=q2.y; B2[2]=q2.z; B2[3]=q2.w;
    B3[0]=q3.x; B3[1]=q3.y; B3[2]=q3.z; B3[3]=q3.w;
    E1[0]=q4.x; E1[1]=q4.y; E1[2]=q4.z; E1[3]=q4.w;
  }
  __half2 outq[4];
#pragma unroll
  for (int i = 0; i < 4; ++i) {
    float cvv = 0.0f;
    if (hasD) {
      float s = fabsf(B0[i] - A0[i]) + fabsf(B1[i] - A1[i]) +
                fabsf(B2[i] - A2[i]) + fabsf(B3[i] - A3[i]);
      s = (s + E1[i]) * 0.25f;
      cvv = 1.0f / (1.0f + (s * s) / KK);
    }
    float chv = 0.0f;
    if (i < 3 || hasR) {
      float s = fabsf(A0[i + 1] - A0[i]) + fabsf(A1[i + 1] - A1[i]) +
                fabsf(A2[i + 1] - A2[i]) + fabsf(A3[i + 1] - A3[i]);
      s = (s + E0[i + 1]) * 0.25f;
      chv = 1.0f / (1.0f + (s * s) / KK);
    }
    outq[i] = __floats2half2_rn(cvv, chv);
  }
  *(float4*)(cp + row) = *(const float4*)outq;
}

// ---------------- fused diffuse + 8x8 block-mean ratio, 4 px/thread (round-4 exact) ----
// Block (32,8) covers a 128x8 tile = 16 pool blocks. FINAL: apply own ratio + subtract shift.
template <bool FIRST, bool FINAL>
__global__ void k_diffuse_ratio(const float* __restrict__ in, const float* __restrict__ ratio_in,
                                const float* __restrict__ shiftp,
                                const __half2* __restrict__ cvh, const float* __restrict__ src,
                                const float* __restrict__ mask, float* __restrict__ out,
                                float* __restrict__ ratio_out) {
  int b = blockIdx.z, tx = threadIdx.x, ty = threadIdx.y;
  int x0 = blockIdx.x * 128 + tx * 4;
  int y = blockIdx.y * 8 + ty;
  float sh = shiftp[0];
  float addv = FIRST ? sh : 0.0f;
  size_t base = (size_t)b * H * W;
  const float* I = in + base;
  const __half2* cp = cvh + base;
  float rq = 1.f, rup = 1.f, rdn = 1.f, rlf = 1.f, rrt = 1.f;
  if (!FIRST) {
    const float* rb = ratio_in + (size_t)b * SH * SW;
    int bx3 = x0 >> 3, byq = y >> 3;
    rq = rb[byq * SW + bx3];
    rup = (y > 0) ? rb[((y - 1) >> 3) * SW + bx3] : 1.f;
    rdn = (y < H - 1) ? rb[((y + 1) >> 3) * SW + bx3] : 1.f;
    rlf = (x0 > 0) ? rb[byq * SW + ((x0 - 1) >> 3)] : 1.f;
    rrt = (x0 + 4 < W) ? rb[byq * SW + ((x0 + 4) >> 3)] : 1.f;
  }
  size_t row = (size_t)y * W + x0;
  bool hasU = (y > 0), hasD = (y < H - 1);
  float4 c4 = *(const float4*)(I + row);
  float C[4] = {(c4.x + addv) * rq, (c4.y + addv) * rq, (c4.z + addv) * rq, (c4.w + addv) * rq};
  float U[4] = {0, 0, 0, 0}, D[4] = {0, 0, 0, 0};
  if (hasU) {
    float4 u4 = *(const float4*)(I + row - W);
    U[0] = (u4.x + addv) * rup; U[1] = (u4.y + addv) * rup;
    U[2] = (u4.z + addv) * rup; U[3] = (u4.w + addv) * rup;
  }
  if (hasD) {
    float4 d4 = *(const float4*)(I + row + W);
    D[0] = (d4.x + addv) * rdn; D[1] = (d4.y + addv) * rdn;
    D[2] = (d4.z + addv) * rdn; D[3] = (d4.w + addv) * rdn;
  }
  float lf = (x0 > 0) ? (I[row - 1] + addv) * rlf : 0.f;
  float rt = (x0 + 4 < W) ? (I[row + 4] + addv) * rrt : 0.f;
  // coefficients (cv own row, cv row above, ch own row + left scalar)
  float4 ccraw = *(const float4*)(cp + row);
  const __half2* hq = (const __half2*)&ccraw;
  float cvq[4], chq[4];
#pragma unroll
  for (int i = 0; i < 4; ++i) {
    float2 tt = __half22float2(hq[i]);
    cvq[i] = tt.x; chq[i] = tt.y;
  }
  float cvu[4] = {0, 0, 0, 0};
  if (hasU) {
    float4 cu = *(const float4*)(cp + row - W);
    const __half2* hu = (const __half2*)&cu;
#pragma unroll
    for (int i = 0; i < 4; ++i) cvu[i] = __half2float(hu[i].x);
  }
  float chl = (x0 > 0) ? __half2float(cp[row - 1].y) : 0.f;
  float acc[4];
#pragma unroll
  for (int i = 0; i < 4; ++i) {
    float L = (i == 0) ? lf : C[i - 1];
    float R = (i == 3) ? rt : C[i + 1];
    float cL = (i == 0) ? chl : chq[i - 1];
    float a = C[i];
    if (hasD) a += LAM * cvq[i] * (D[i] - C[i]);
    if (hasU) a -= LAM * cvu[i] * (C[i] - U[i]);
    if (i < 3 || x0 + 4 < W) a += LAM * chq[i] * (R - C[i]);
    if (i > 0 || x0 > 0) a -= LAM * cL * (C[i] - L);
    acc[i] = a;
  }
  // 8x8 block-mean -> ratio
  __shared__ float sd[8][32];
  __shared__ float rblk[16];
  sd[ty][tx] = acc[0] + acc[1] + acc[2] + acc[3];
  __syncthreads();
  if (ty == 0) {  // lanes 0..31 of wave 0
    float colsum = 0.f;
#pragma unroll
    for (int r = 0; r < 8; ++r) colsum += sd[r][tx];
    float s = colsum + __shfl_down(colsum, 1);
    if ((tx & 1) == 0) {
      int pb = tx >> 1;
      size_t si = ((size_t)b * SH + blockIdx.y) * SW + (blockIdx.x * 16 + pb);
      float mean = s * (1.0f / 64.0f);
      float rv = (mask[si] < 0.5f) ? 1.0f : (src[si] + sh) / (mean + 1e-8f);
      if (FINAL) rblk[pb] = rv;
      else ratio_out[si] = rv;
    }
  }
  if (FINAL) {
    __syncthreads();
    float rv = rblk[tx >> 1];
    float4 o = make_float4(acc[0] * rv - sh, acc[1] * rv - sh, acc[2] * rv - sh, acc[3] * rv - sh);
    *(float4*)(out + base + row) = o;
  } else {
    *(float4*)(out + base + row) = make_float4(acc[0], acc[1], acc[2], acc[3]);
  }
}

}  // namespace

extern "C" void kernel_launch(void* const* d_in, const int* in_sizes, int n_in, void* d_out,
                              int out_size, void* d_ws, size_t ws_size, hipStream_t stream) {
  (void)in_sizes; (void)n_in; (void)out_size; (void)ws_size;
  const float* guide = (const float*)d_in[0];
  const float* source = (const float*)d_in[1];
  const float* mask = (const float*)d_in[2];
  const float* ybic = (const float*)d_in[3];
  float* out = (float*)d_out;

  char* ws = (char*)d_ws;
  float2* A = (float2*)ws;                                  // [0,32MB)
  float2* Bc = (float2*)(ws + (size_t)32 * 1024 * 1024);    // [32,48MB)
  __half2* cvh = (__half2*)(ws + (size_t)48 * 1024 * 1024); // [48,64MB)
  float* er = (float*)(ws + (size_t)80 * 1024 * 1024);      // [80,96MB) (Bc live during invg)
  float* bufA = (float*)ws;                                 // overlays A (dead after invg)
  float* bufB = (float*)(ws + (size_t)16 * 1024 * 1024);
  float* shiftp = (float*)(ws + (size_t)64 * 1024 * 1024);
  float* partial = shiftp + 64;
  float* ratioA = (float*)(ws + (size_t)64 * 1024 * 1024 + 4096);
  float* ratioB = ratioA + (size_t)NB * SH * SW;

  k_shift_part<<<64, 256, 0, stream>>>(source, partial);
  k_shift_fin<<<1, 64, 0, stream>>>(partial, shiftp);

  k_rowfft_fwd<<<dim3(H / 2, NB), 256, 0, stream>>>(guide, ybic, shiftp, A);
  dim3 gT(NCOL / 32, H / 32, NB), bT(32, 8);
  k_transpose_fwd<<<gT, bT, 0, stream>>>(A, Bc);
  k_colfft_mask<<<dim3(NCOL, NB), 256, 0, stream>>>(Bc);
  // split backend (fused invcoeffs was a net loss -- r2/r3 audit): inverse row FFT with
  // Bc gather (no backward transpose), then the round-0 coeffs kernel.
  k_rowfft_invg<<<dim3(H, NB), 256, 0, stream>>>(A, Bc, er);
  k_coeffs<<<dim3(H, NB), 256, 0, stream>>>(guide, ybic, er, cvh);

  // 8 diffusion iterations, plain launches (round-4 proven path)
  dim3 gD(W / 128, H / 8, NB), bD(32, 8);
  k_diffuse_ratio<true, false><<<gD, bD, 0, stream>>>(ybic, nullptr, shiftp, cvh, source, mask,
                                                      bufA, ratioA);
  k_diffuse_ratio<false, false><<<gD, bD, 0, stream>>>(bufA, ratioA, shiftp, cvh, source, mask,
                                                       bufB, ratioB);
  k_diffuse_ratio<false, false><<<gD, bD, 0, stream>>>(bufB, ratioB, shiftp, cvh, source, mask,
                                                       bufA, ratioA);
  k_diffuse_ratio<false, false><<<gD, bD, 0, stream>>>(bufA, ratioA, shiftp, cvh, source, mask,
                                                       bufB, ratioB);
  k_diffuse_ratio<false, false><<<gD, bD, 0, stream>>>(bufB, ratioB, shiftp, cvh, source, mask,
                                                       bufA, ratioA);
  k_diffuse_ratio<false, false><<<gD, bD, 0, stream>>>(bufA, ratioA, shiftp, cvh, source, mask,
                                                       bufB, ratioB);
  k_diffuse_ratio<false, false><<<gD, bD, 0, stream>>>(bufB, ratioB, shiftp, cvh, source, mask,
                                                       bufA, ratioA);
  // it 7 (FINAL): bufA -> out, applies own ratio + subtracts shift in-kernel
  k_diffuse_ratio<false, true><<<gD, bD, 0, stream>>>(bufA, ratioA, shiftp, cvh, source, mask,
                                                      out, ratioB);
}

// Round 9
// 286.986 us; speedup vs baseline: 1.0703x; 1.0703x over previous
//
#include <hip/hip_runtime.h>
#include <hip/hip_fp16.h>

namespace {

constexpr int H = 1024, W = 1024, NB = 4;
constexpr int SH = 128, SW = 128;
constexpr float LAM = 0.24f;
constexpr float KK = 0.03f * 0.03f;
constexpr float DEPS_V = 0.1f;
constexpr float FFT_SCALE = 1.0f / (1024.0f * 1024.0f);  // ortho fwd+inv combined
// Processed (masked) columns: |x(k2)| <= 0.5  <=>  k2 in [256, 768). Margin to the
// 0.25 boundary ~1.5e-3 >> fp error.
constexpr int COL_LO = 256, NCOL = 512;
constexpr int NTW = 340;  // twiddle entries: NS=4(4) + 16(16) + 64(64) + 256(256)

__device__ __forceinline__ float2 cadd(float2 a, float2 b) { return make_float2(a.x + b.x, a.y + b.y); }
__device__ __forceinline__ float2 csub(float2 a, float2 b) { return make_float2(a.x - b.x, a.y - b.y); }
__device__ __forceinline__ float2 cmul(float2 a, float2 b) {
  return make_float2(a.x * b.x - a.y * b.y, a.x * b.y + a.y * b.x);
}
__device__ __forceinline__ int phys2(int e) { return e + (e >> 4); }

// Twiddle table: per direction, 340 entries. Entry for (NS,p) at offset (NS-4)/3 + p,
// value = (cs, sn) of sincospif(sign * p * (1/(2NS))) -- the EXACT expression the
// butterfly used inline, so results are bit-identical.
__device__ __forceinline__ void build_tw(float2* tw, float sign, int tid, int nth) {
  for (int i = tid; i < NTW; i += nth) {
    int NS, p;
    if (i < 4) { NS = 4; p = i; }
    else if (i < 20) { NS = 16; p = i - 4; }
    else if (i < 84) { NS = 64; p = i - 20; }
    else { NS = 256; p = i - 84; }
    float sn, cs;
    sincospif(sign * (float)p * (1.0f / (float)(2 * NS)), &sn, &cs);
    tw[i] = make_float2(cs, sn);
  }
}

// ---------------- min(source): 2-stage parallel reduction ----------------
__global__ void k_shift_part(const float* __restrict__ src, float* __restrict__ partial) {
  int t = threadIdx.x;
  int b0 = blockIdx.x * 1024;
  float m = fminf(fminf(src[b0 + t], src[b0 + t + 256]),
                  fminf(src[b0 + t + 512], src[b0 + t + 768]));
  for (int o = 32; o > 0; o >>= 1) m = fminf(m, __shfl_xor(m, o));
  __shared__ float sm[4];
  if ((t & 63) == 0) sm[t >> 6] = m;
  __syncthreads();
  if (t == 0) partial[blockIdx.x] = fminf(fminf(sm[0], sm[1]), fminf(sm[2], sm[3]));
}

__global__ void k_shift_fin(const float* __restrict__ partial, float* __restrict__ shiftp) {
  int t = threadIdx.x;  // 64 threads
  float m = partial[t];
  for (int o = 32; o > 0; o >>= 1) m = fminf(m, __shfl_xor(m, o));
  if (t == 0) shiftp[0] = (m <= DEPS_V) ? DEPS_V : 0.0f;
}

// ---------------- Stockham radix-4 1024-pt FFT (natural in -> natural out) ----------------
template <int NS, bool INV>
__device__ __forceinline__ void r4_butterfly(float2 v[4], int j, float2 r[4],
                                             const float2* __restrict__ tw) {
  if (NS > 1) {
    int p = j & (NS - 1);
    float2 w1 = tw[(NS - 4) / 3 + p];   // (cs, sn), direction baked into the table
    float2 w2 = cmul(w1, w1);
    float2 w3 = cmul(w2, w1);
    v[1] = cmul(v[1], w1);
    v[2] = cmul(v[2], w2);
    v[3] = cmul(v[3], w3);
  }
  float2 a0 = cadd(v[0], v[2]), a2 = csub(v[0], v[2]);
  float2 a1 = cadd(v[1], v[3]), a3 = csub(v[1], v[3]);
  a3 = INV ? make_float2(-a3.y, a3.x) : make_float2(a3.y, -a3.x);
  r[0] = cadd(a0, a1);
  r[2] = csub(a0, a1);
  r[1] = cadd(a2, a3);
  r[3] = csub(a2, a3);
}

template <int NS, bool INV>
__device__ __forceinline__ void r4_stage_lds(float2 v[4], float2* dst, int j,
                                             const float2* __restrict__ tw) {
  float2 r[4];
  r4_butterfly<NS, INV>(v, j, r, tw);
  int p = j & (NS - 1);
  int base = ((j - p) << 2) + p;
#pragma unroll
  for (int k = 0; k < 4; ++k) dst[phys2(base + k * NS)] = r[k];
}

__device__ __forceinline__ void lds_load4(const float2* src, float2 v[4], int j) {
#pragma unroll
  for (int k = 0; k < 4; ++k) v[k] = src[phys2(j + k * 256)];
}

// tw must be built before the call; the barrier after stage NS=1 orders table
// writes before the first table read (NS=4 stage).
template <bool INV>
__device__ void fft1024(float2 v[4], float2* b0, float2* b1, int j,
                        const float2* __restrict__ tw) {
  r4_stage_lds<1, INV>(v, b0, j, tw);
  __syncthreads();
  lds_load4(b0, v, j);
  r4_stage_lds<4, INV>(v, b1, j, tw);
  __syncthreads();
  lds_load4(b1, v, j);
  r4_stage_lds<16, INV>(v, b0, j, tw);
  __syncthreads();
  lds_load4(b0, v, j);
  r4_stage_lds<64, INV>(v, b1, j, tw);
  __syncthreads();
  lds_load4(b1, v, j);
  float2 r[4];
  r4_butterfly<256, INV>(v, j, r, tw);
#pragma unroll
  for (int k = 0; k < 4; ++k) v[k] = r[k];
}

// ---------------- forward row FFT, 2 real rows packed per complex transform ----------------
// Z = S(2y) + i*S(2y+1); F0[k] = (Z[k]+conj(Z[-k]))/2, F1[k] = -i(Z[k]-conj(Z[-k]))/2.
__global__ void k_rowfft_fwd(const float* __restrict__ guide, const float* __restrict__ ybic,
                             const float* __restrict__ shiftp, float2* __restrict__ A) {
  __shared__ float2 b0[1088], b1[1088];
  __shared__ float2 twf[NTW];
  int b = blockIdx.y, y0 = blockIdx.x * 2, j = threadIdx.x;
  build_tw(twf, -1.0f, j, 256);
  float sh = shiftp[0];
  const float* g0 = guide + ((size_t)(b * 3 + 0) * H + y0) * W;
  const float* g1 = guide + ((size_t)(b * 3 + 1) * H + y0) * W;
  const float* g2 = guide + ((size_t)(b * 3 + 2) * H + y0) * W;
  const float* yb = ybic + ((size_t)b * H + y0) * W;
  float2 v[4];
#pragma unroll
  for (int k = 0; k < 4; ++k) {
    int x = j + k * 256;
    float s0 = g0[x] + g1[x] + g2[x] + (yb[x] + sh);
    float s1 = g0[x + W] + g1[x + W] + g2[x + W] + (yb[x + W] + sh);
    v[k] = make_float2(s0, s1);
  }
  fft1024<false>(v, b0, b1, j, twf);
#pragma unroll
  for (int k = 0; k < 4; ++k) b0[phys2(j + k * 256)] = v[k];
  __syncthreads();
  float2* o0 = A + ((size_t)b * H + y0) * W;
  float2* o1 = o0 + W;
#pragma unroll
  for (int k = 0; k < 4; ++k) {
    int m = j + k * 256;
    float2 Zm = v[k];
    float2 Zc = b0[phys2((1024 - m) & 1023)];
    o0[m] = make_float2(0.5f * (Zm.x + Zc.x), 0.5f * (Zm.y - Zc.y));
    o1[m] = make_float2(0.5f * (Zm.y + Zc.y), 0.5f * (Zc.x - Zm.x));
  }
}

// ---------------- forward transpose: columns [256,768) -> Bc col-major ----------------
__global__ void k_transpose_fwd(const float2* __restrict__ A, float2* __restrict__ Bc) {
  __shared__ float2 tile[32][33];
  int b = blockIdx.z;
  int c0 = blockIdx.x * 32, y0 = blockIdx.y * 32;
  const float2* ip = A + (size_t)b * H * W;
  float2* op = Bc + (size_t)b * NCOL * H;
#pragma unroll
  for (int k = 0; k < 4; ++k)
    tile[threadIdx.y + k * 8][threadIdx.x] =
        ip[(size_t)(y0 + threadIdx.y + k * 8) * W + (COL_LO + c0 + threadIdx.x)];
  __syncthreads();
#pragma unroll
  for (int k = 0; k < 4; ++k)
    op[(size_t)(c0 + threadIdx.y + k * 8) * H + (y0 + threadIdx.x)] =
        tile[threadIdx.x][threadIdx.y + k * 8];
}

// ---------------- column FFT + radial mask + inverse column FFT ----------------
__global__ void k_colfft_mask(float2* __restrict__ Bc) {
  __shared__ float2 b0[1088], b1[1088];
  __shared__ float2 twf[NTW], twi[NTW];
  int b = blockIdx.y, r = blockIdx.x, j = threadIdx.x;
  build_tw(twf, -1.0f, j, 256);
  build_tw(twi, 1.0f, j, 256);
  int k2 = COL_LO + r;
  double xj = -1.0 + 2.0 * (double)k2 / 1023.0;
  double xj2 = xj * xj;
  float2* row = Bc + ((size_t)b * NCOL + r) * H;
  float2 v[4];
#pragma unroll
  for (int k = 0; k < 4; ++k) v[k] = row[j + k * 256];
  fft1024<false>(v, b0, b1, j, twf);
#pragma unroll
  for (int k = 0; k < 4; ++k) {
    int i = j + k * 256;
    double yv = -1.0 + 2.0 * (double)i / 1023.0;
    if (xj2 + yv * yv <= 0.25) v[k] = make_float2(0.0f, 0.0f);
  }
  __syncthreads();   // b0/b1 reuse between the two transforms
  fft1024<true>(v, b0, b1, j, twi);
#pragma unroll
  for (int k = 0; k < 4; ++k) row[j + k * 256] = v[k];
}

// ---------------- fused inverse row FFT + Perona-Malik coefficients ----------------
// 4-row block (round-4 proven version): Bc cols staged in registers; er in a 2-row
// LDS ring; no cross-FFT register prefetch (round-5 showed it spills to scratch).
__global__ __launch_bounds__(256, 4) void k_invcoeffs(
    const float2* __restrict__ A, const float2* __restrict__ Bc,
    const float* __restrict__ guide, const float* __restrict__ ybic,
    __half2* __restrict__ cvh) {
  __shared__ float2 b0[1088], b1[1088];
  __shared__ float erbuf[2][1028];    // er rows ring buffer
  __shared__ float2 twi[NTW];
  const int b = blockIdx.y, j = threadIdx.x;
  const int y0 = blockIdx.x * 4;
  build_tw(twi, 1.0f, j, 256);
  const float2* Ab = A + (size_t)b * H * W;
  const float* g = guide + (size_t)b * 3 * H * W;
  const float* yb = ybic + (size_t)b * H * W;
  __half2* cpo = cvh + (size_t)b * H * W;
  const size_t CH = (size_t)H * W;

  // register stage: thread j holds Bc rows y0..y0+4 for cols j and j+256
  float2 c0r0, c0r1, c0r2, c0r3, c0r4;
  float2 c1r0, c1r1, c1r2, c1r3, c1r4;
  {
    const float2* bp0 = Bc + ((size_t)b * NCOL + j) * H + y0;
    const float2* bp1 = Bc + ((size_t)b * NCOL + (j + 256)) * H + y0;
    float4 p01 = *(const float4*)bp0;
    float4 p23 = *(const float4*)(bp0 + 2);
    c0r0 = make_float2(p01.x, p01.y);
    c0r1 = make_float2(p01.z, p01.w);
    c0r2 = make_float2(p23.x, p23.y);
    c0r3 = make_float2(p23.z, p23.w);
    c0r4 = (y0 + 4 < H) ? bp0[4] : make_float2(0.f, 0.f);
    float4 q01 = *(const float4*)bp1;
    float4 q23 = *(const float4*)(bp1 + 2);
    c1r0 = make_float2(q01.x, q01.y);
    c1r1 = make_float2(q01.z, q01.w);
    c1r2 = make_float2(q23.x, q23.y);
    c1r3 = make_float2(q23.z, q23.w);
    c1r4 = (y0 + 4 < H) ? bp1[4] : make_float2(0.f, 0.f);
  }

  const int x0 = j * 4;
  for (int r = 0; r < 5; ++r) {
    int yf = y0 + r;
    if (yf < H) {  // block-uniform (y0, r uniform) -> syncs inside are safe
      const float2* arow = Ab + (size_t)yf * W;
      float2 v[4];
      float2 a0 = arow[j], a3 = arow[j + 768];
      v[0] = make_float2(a0.x * 1024.0f, a0.y * 1024.0f);
      v[3] = make_float2(a3.x * 1024.0f, a3.y * 1024.0f);
      v[1] = c0r0;
      v[2] = c1r0;
      fft1024<true>(v, b0, b1, j, twi);
#pragma unroll
      for (int k = 0; k < 4; ++k) erbuf[r & 1][j + k * 256] = v[k].x * FFT_SCALE;
    }
    // rotate register stage (constant indices only -- avoids scratch spill)
    c0r0 = c0r1; c0r1 = c0r2; c0r2 = c0r3; c0r3 = c0r4;
    c1r0 = c1r1; c1r1 = c1r2; c1r2 = c1r3; c1r3 = c1r4;
    __syncthreads();
    if (r >= 1) {
      // coeffs for row y = y0 + r - 1 (exact port of k_coeffs, er from LDS)
      int y = y0 + r - 1;
      size_t row = (size_t)y * W + x0;
      float4 a0 = *(const float4*)(g + row);
      float4 a1 = *(const float4*)(g + CH + row);
      float4 a2 = *(const float4*)(g + 2 * CH + row);
      float4 a3 = *(const float4*)(yb + row);
      float4 e0 = *(const float4*)&erbuf[(r - 1) & 1][x0];
      float A0[5] = {a0.x, a0.y, a0.z, a0.w, 0.f};
      float A1[5] = {a1.x, a1.y, a1.z, a1.w, 0.f};
      float A2[5] = {a2.x, a2.y, a2.z, a2.w, 0.f};
      float A3[5] = {a3.x, a3.y, a3.z, a3.w, 0.f};
      float E0[5] = {e0.x, e0.y, e0.z, e0.w, 0.f};
      bool hasR = (x0 + 4 < W);
      if (hasR) {
        A0[4] = g[row + 4]; A1[4] = g[CH + row + 4]; A2[4] = g[2 * CH + row + 4];
        A3[4] = yb[row + 4]; E0[4] = erbuf[(r - 1) & 1][x0 + 4];
      }
      float B0[4], B1[4], B2[4], B3[4], E1[4];
      bool hasD = (y < H - 1);
      if (hasD) {
        float4 q0 = *(const float4*)(g + row + W);
        float4 q1 = *(const float4*)(g + CH + row + W);
        float4 q2 = *(const float4*)(g + 2 * CH + row + W);
        float4 q3 = *(const float4*)(yb + row + W);
        float4 q4 = *(const float4*)&erbuf[r & 1][x0];
        B0[0]=q0.x; B0[1]=q0.y; B0[2]=q0.z; B0[3]=q0.w;
        B1[0]=q1.x; B1[1]=q1.y; B1[2]=q1.z; B1[3]=q1.w;
        B2[0]=q2.x; B2[1]=q2.y; B2[2]=q2.z; B2[3]=q2.w;
        B3[0]=q3.x; B3[1]=q3.y; B3[2]=q3.z; B3[3]=q3.w;
        E1[0]=q4.x; E1[1]=q4.y; E1[2]=q4.z; E1[3]=q4.w;
      }
      __half2 outq[4];
#pragma unroll
      for (int i = 0; i < 4; ++i) {
        float cvv = 0.0f;
        if (hasD) {
          float s = fabsf(B0[i] - A0[i]) + fabsf(B1[i] - A1[i]) +
                    fabsf(B2[i] - A2[i]) + fabsf(B3[i] - A3[i]);
          s = (s + E1[i]) * 0.25f;
          cvv = 1.0f / (1.0f + (s * s) / KK);
        }
        float chv = 0.0f;
        if (i < 3 || hasR) {
          float s = fabsf(A0[i + 1] - A0[i]) + fabsf(A1[i + 1] - A1[i]) +
                    fabsf(A2[i + 1] - A2[i]) + fabsf(A3[i + 1] - A3[i]);
          s = (s + E0[i + 1]) * 0.25f;
          chv = 1.0f / (1.0f + (s * s) / KK);
        }
        outq[i] = __floats2half2_rn(cvv, chv);
      }
      *(float4*)(cpo + row) = *(const float4*)outq;
    }
    __syncthreads();
  }
}

// ---------------- fused diffuse + 8x8 block-mean ratio, 4 px/thread (round-4 exact) ----
// Block (32,8) covers a 128x8 tile = 16 pool blocks. FINAL: apply own ratio + subtract shift.
template <bool FIRST, bool FINAL>
__global__ void k_diffuse_ratio(const float* __restrict__ in, const float* __restrict__ ratio_in,
                                const float* __restrict__ shiftp,
                                const __half2* __restrict__ cvh, const float* __restrict__ src,
                                const float* __restrict__ mask, float* __restrict__ out,
                                float* __restrict__ ratio_out) {
  int b = blockIdx.z, tx = threadIdx.x, ty = threadIdx.y;
  int x0 = blockIdx.x * 128 + tx * 4;
  int y = blockIdx.y * 8 + ty;
  float sh = shiftp[0];
  float addv = FIRST ? sh : 0.0f;
  size_t base = (size_t)b * H * W;
  const float* I = in + base;
  const __half2* cp = cvh + base;
  float rq = 1.f, rup = 1.f, rdn = 1.f, rlf = 1.f, rrt = 1.f;
  if (!FIRST) {
    const float* rb = ratio_in + (size_t)b * SH * SW;
    int bx3 = x0 >> 3, byq = y >> 3;
    rq = rb[byq * SW + bx3];
    rup = (y > 0) ? rb[((y - 1) >> 3) * SW + bx3] : 1.f;
    rdn = (y < H - 1) ? rb[((y + 1) >> 3) * SW + bx3] : 1.f;
    rlf = (x0 > 0) ? rb[byq * SW + ((x0 - 1) >> 3)] : 1.f;
    rrt = (x0 + 4 < W) ? rb[byq * SW + ((x0 + 4) >> 3)] : 1.f;
  }
  size_t row = (size_t)y * W + x0;
  bool hasU = (y > 0), hasD = (y < H - 1);
  float4 c4 = *(const float4*)(I + row);
  float C[4] = {(c4.x + addv) * rq, (c4.y + addv) * rq, (c4.z + addv) * rq, (c4.w + addv) * rq};
  float U[4] = {0, 0, 0, 0}, D[4] = {0, 0, 0, 0};
  if (hasU) {
    float4 u4 = *(const float4*)(I + row - W);
    U[0] = (u4.x + addv) * rup; U[1] = (u4.y + addv) * rup;
    U[2] = (u4.z + addv) * rup; U[3] = (u4.w + addv) * rup;
  }
  if (hasD) {
    float4 d4 = *(const float4*)(I + row + W);
    D[0] = (d4.x + addv) * rdn; D[1] = (d4.y + addv) * rdn;
    D[2] = (d4.z + addv) * rdn; D[3] = (d4.w + addv) * rdn;
  }
  float lf = (x0 > 0) ? (I[row - 1] + addv) * rlf : 0.f;
  float rt = (x0 + 4 < W) ? (I[row + 4] + addv) * rrt : 0.f;
  // coefficients (cv own row, cv row above, ch own row + left scalar)
  float4 ccraw = *(const float4*)(cp + row);
  const __half2* hq = (const __half2*)&ccraw;
  float cvq[4], chq[4];
#pragma unroll
  for (int i = 0; i < 4; ++i) {
    float2 tt = __half22float2(hq[i]);
    cvq[i] = tt.x; chq[i] = tt.y;
  }
  float cvu[4] = {0, 0, 0, 0};
  if (hasU) {
    float4 cu = *(const float4*)(cp + row - W);
    const __half2* hu = (const __half2*)&cu;
#pragma unroll
    for (int i = 0; i < 4; ++i) cvu[i] = __half2float(hu[i].x);
  }
  float chl = (x0 > 0) ? __half2float(cp[row - 1].y) : 0.f;
  float acc[4];
#pragma unroll
  for (int i = 0; i < 4; ++i) {
    float L = (i == 0) ? lf : C[i - 1];
    float R = (i == 3) ? rt : C[i + 1];
    float cL = (i == 0) ? chl : chq[i - 1];
    float a = C[i];
    if (hasD) a += LAM * cvq[i] * (D[i] - C[i]);
    if (hasU) a -= LAM * cvu[i] * (C[i] - U[i]);
    if (i < 3 || x0 + 4 < W) a += LAM * chq[i] * (R - C[i]);
    if (i > 0 || x0 > 0) a -= LAM * cL * (C[i] - L);
    acc[i] = a;
  }
  // 8x8 block-mean -> ratio
  __shared__ float sd[8][32];
  __shared__ float rblk[16];
  sd[ty][tx] = acc[0] + acc[1] + acc[2] + acc[3];
  __syncthreads();
  if (ty == 0) {  // lanes 0..31 of wave 0
    float colsum = 0.f;
#pragma unroll
    for (int r = 0; r < 8; ++r) colsum += sd[r][tx];
    float s = colsum + __shfl_down(colsum, 1);
    if ((tx & 1) == 0) {
      int pb = tx >> 1;
      size_t si = ((size_t)b * SH + blockIdx.y) * SW + (blockIdx.x * 16 + pb);
      float mean = s * (1.0f / 64.0f);
      float rv = (mask[si] < 0.5f) ? 1.0f : (src[si] + sh) / (mean + 1e-8f);
      if (FINAL) rblk[pb] = rv;
      else ratio_out[si] = rv;
    }
  }
  if (FINAL) {
    __syncthreads();
    float rv = rblk[tx >> 1];
    float4 o = make_float4(acc[0] * rv - sh, acc[1] * rv - sh, acc[2] * rv - sh, acc[3] * rv - sh);
    *(float4*)(out + base + row) = o;
  } else {
    *(float4*)(out + base + row) = make_float4(acc[0], acc[1], acc[2], acc[3]);
  }
}

}  // namespace

extern "C" void kernel_launch(void* const* d_in, const int* in_sizes, int n_in, void* d_out,
                              int out_size, void* d_ws, size_t ws_size, hipStream_t stream) {
  (void)in_sizes; (void)n_in; (void)out_size; (void)ws_size;
  const float* guide = (const float*)d_in[0];
  const float* source = (const float*)d_in[1];
  const float* mask = (const float*)d_in[2];
  const float* ybic = (const float*)d_in[3];
  float* out = (float*)d_out;

  char* ws = (char*)d_ws;
  float2* A = (float2*)ws;                                  // [0,32MB)
  float2* Bc = (float2*)(ws + (size_t)32 * 1024 * 1024);    // [32,48MB)
  __half2* cvh = (__half2*)(ws + (size_t)48 * 1024 * 1024); // [48,64MB)
  float* itmp = (float*)ws;                                 // overlays A (dead after invcoeffs)
  float* shiftp = (float*)(ws + (size_t)64 * 1024 * 1024);
  float* partial = shiftp + 64;
  float* ratioA = (float*)(ws + (size_t)64 * 1024 * 1024 + 4096);
  float* ratioB = ratioA + (size_t)NB * SH * SW;

  k_shift_part<<<64, 256, 0, stream>>>(source, partial);
  k_shift_fin<<<1, 64, 0, stream>>>(partial, shiftp);

  k_rowfft_fwd<<<dim3(H / 2, NB), 256, 0, stream>>>(guide, ybic, shiftp, A);
  dim3 gT(NCOL / 32, H / 32, NB), bT(32, 8);
  k_transpose_fwd<<<gT, bT, 0, stream>>>(A, Bc);
  k_colfft_mask<<<dim3(NCOL, NB), 256, 0, stream>>>(Bc);
  // fused: backward transpose + inverse row FFT + coeffs (er never hits HBM)
  k_invcoeffs<<<dim3(H / 4, NB), 256, 0, stream>>>(A, Bc, guide, ybic, cvh);

  dim3 gD(W / 128, H / 8, NB), bD(32, 8);
  // it 0: ybic -> itmp (adds shift, no ratio)
  k_diffuse_ratio<true, false><<<gD, bD, 0, stream>>>(ybic, nullptr, shiftp, cvh, source, mask,
                                                      itmp, ratioA);
  // its 1..6: ping-pong
  k_diffuse_ratio<false, false><<<gD, bD, 0, stream>>>(itmp, ratioA, shiftp, cvh, source, mask,
                                                       out, ratioB);
  k_diffuse_ratio<false, false><<<gD, bD, 0, stream>>>(out, ratioB, shiftp, cvh, source, mask,
                                                       itmp, ratioA);
  k_diffuse_ratio<false, false><<<gD, bD, 0, stream>>>(itmp, ratioA, shiftp, cvh, source, mask,
                                                       out, ratioB);
  k_diffuse_ratio<false, false><<<gD, bD, 0, stream>>>(out, ratioB, shiftp, cvh, source, mask,
                                                       itmp, ratioA);
  k_diffuse_ratio<false, false><<<gD, bD, 0, stream>>>(itmp, ratioA, shiftp, cvh, source, mask,
                                                       out, ratioB);
  k_diffuse_ratio<false, false><<<gD, bD, 0, stream>>>(out, ratioB, shiftp, cvh, source, mask,
                                                       itmp, ratioA);
  // it 7 (FINAL): itmp -> out, applies own ratio + subtracts shift in-kernel
  k_diffuse_ratio<false, true><<<gD, bD, 0, stream>>>(itmp, ratioA, shiftp, cvh, source, mask,
                                                      out, ratioB);
}